// Round 6
// baseline (418.159 us; speedup 1.0000x reference)
//
#include <hip/hip_runtime.h>

// Problem constants
#define B_   32
#define CIN  256
#define H_   64
#define W_   64
#define COUT 512
#define G_   9
#define CPG_IN  28          // 252 used input channels / 9 groups
#define HW_  (H_*W_)        // 4096
#define HW4_ (HW_/4)        // 1024 float4 per plane
#define VSTRIDE 16          // v padded to [512][16] for aligned scalar loads

typedef float f4 __attribute__((ext_vector_type(4)));

// ---------------------------------------------------------------------------
// Kernel A: v[o][g] = sum of w_pw[o, c] over group g's columns.
// g = c/56 for c < 504; c in [504,512) folds into centre group 4 (channel 252's
// group, the unshifted centre tap). One block (64 threads) per o.
// ---------------------------------------------------------------------------
__global__ __launch_bounds__(64) void reduce_w_kernel(const float* __restrict__ w,
                                                      float* __restrict__ v) {
    const int o = blockIdx.x;
    const int t = threadIdx.x;          // 0..63
    const float* row = w + o * COUT;
#pragma unroll
    for (int g = 0; g < G_; ++g) {
        float val = (t < 56) ? row[g * 56 + t] : 0.0f;
        if (g == 4 && t >= 56) val = row[504 + (t - 56)];   // miss channels -> centre
#pragma unroll
        for (int off = 32; off; off >>= 1) val += __shfl_down(val, off);
        if (t == 0) v[o * VSTRIDE + g] = val;
    }
}

// ---------------------------------------------------------------------------
// Fused BC kernel: one block = output tile (b, 8 rows, 32 cols) x ALL 512 o.
//   Phase 1: build private s-tile sl[9][10][40 cols] (cols w0-4..w0+35, rows
//            h0-1..h0+8, zero-padded) directly from x: 900 f4-slots spread
//            over 256 threads (idx = g*100 + r*10 + c4), each slot = 28-deep
//            channel sum via NT f4 loads. No s' intermediate, no halo kernels.
//   Phase 2: per thread (wc 0..7, hl 0..7, o_sub = wave id): 36 oi-invariant
//            LDS scalars, then 128 o's: 9 FMA*4 + one NT f4 store each.
//            v[o][g] index is wave-uniform -> s_load broadcast.
// Why fused: B->C launch boundary serialized the 132 MB read stream against
// the 268 MB write stream (rounds 1-4 all ~360 us, ~40 us above floor);
// blocks here drift through read->write phases independently, overlapping the
// streams chip-wide, and the s' HBM round-trip disappears. Cost: 1.25x x-read
// (row halo). Deadlock-impossible: only __syncthreads, no inter-block waits.
// Occupancy: 512 blocks = 2/CU (LDS 15.8 KB, VGPR<=256 via launch_bounds).
// ---------------------------------------------------------------------------
#define NBC (B_ * 8 * 2)     // 32 b x 8 h-tiles x 2 w-halves = 512 blocks

__global__ __launch_bounds__(256, 2) void fused_bc_kernel(const float* __restrict__ x,
                                                          const float* __restrict__ v,
                                                          float* __restrict__ out) {
    __shared__ float sl[G_][10][44];   // 40 used cols + 4 pad; 15840 B

    const int bid = blockIdx.x;
    const int wh = bid & 1;            // w-half: cols [wh*32, wh*32+32)
    const int ht = (bid >> 1) & 7;     // h-tile: rows [ht*8, ht*8+8)
    const int b  = bid >> 4;           // batch
    const int h0 = ht * 8;
    const int w0 = wh * 32;
    const int tid = threadIdx.x;

    // ---- Phase 1: s-tile from x ----
#pragma unroll 1
    for (int i = 0; i < 4; ++i) {
        const int idx = tid + i * 256;
        if (idx >= 900) break;                    // 9*10*10 slots
        const int g   = idx / 100;
        const int rem = idx - g * 100;
        const int r   = rem / 10;                 // tile row 0..9 (global h0-1+r)
        const int c4  = rem - r * 10;             // f4 col 0..9 (global w0-4+4*c4)
        const int gh  = h0 - 1 + r;
        const int gc  = w0 - 4 + c4 * 4;
        f4 acc = (f4)0.0f;
        if ((unsigned)gh < (unsigned)H_ && (unsigned)gc < (unsigned)W_) {
            const f4* xp = (const f4*)x + (long)(b * CIN + g * CPG_IN) * HW4_
                         + gh * (W_ / 4) + (gc >> 2);
#pragma unroll
            for (int k = 0; k < CPG_IN; ++k)
                acc += __builtin_nontemporal_load(xp + (long)k * HW4_);
        }
        *(f4*)&sl[g][r][c4 * 4] = acc;            // row base 16B-aligned (44*4=176B)
    }
    __syncthreads();

    // ---- Phase 2: 512-o pointwise ----
    const int wc    = tid & 7;         // f4-col 0..7  -> local col wl..wl+3
    const int hl    = (tid >> 3) & 7;  // row 0..7
    const int o_sub = tid >> 6;        // 0..3, wave-uniform -> v via s_load
    const int wl    = wc * 4;

    // oi-invariant s values: out col w0+wl+j uses s global col (w0+wl+j)+gj-1
    // -> sl col wl+gj+3+j; out row h0+hl uses sl row hl+gi. Static-indexed
    // array -> registers (36 VGPRs).
    float sv[G_][4];
#pragma unroll
    for (int g = 0; g < G_; ++g) {
        const int gi = g / 3, gj = g - (g / 3) * 3;
#pragma unroll
        for (int j = 0; j < 4; ++j)
            sv[g][j] = sl[g][hl + gi][wl + gj + 3 + j];
    }

    long obase = (((long)b * COUT + o_sub * 128) * H_ + (h0 + hl)) * W_ + w0 + wl;
    const float* vp = v + (o_sub * 128) * VSTRIDE;
#pragma unroll 4
    for (int oi = 0; oi < 128; ++oi) {
        f4 acc = (f4)0.0f;
#pragma unroll
        for (int g = 0; g < G_; ++g) {
            const float vv = vp[oi * VSTRIDE + g];   // wave-uniform scalar load
            acc.x += vv * sv[g][0];
            acc.y += vv * sv[g][1];
            acc.z += vv * sv[g][2];
            acc.w += vv * sv[g][3];
        }
        // touch-once output -> NT store; 8 lanes = 128 B contiguous per row,
        // wave covers one o-plane's 8-row window
        __builtin_nontemporal_store(acc, (f4*)(out + obase + (long)oi * HW_));
    }
}

// ---------------------------------------------------------------------------
extern "C" void kernel_launch(void* const* d_in, const int* in_sizes, int n_in,
                              void* d_out, int out_size, void* d_ws, size_t ws_size,
                              hipStream_t stream) {
    const float* x    = (const float*)d_in[0];   // (32,256,64,64) fp32
    const float* w_pw = (const float*)d_in[1];   // (512,512) fp32
    float* out = (float*)d_out;                  // (32,512,64,64) fp32

    // workspace: v[512][16] at 0 (32 KiB). No s' intermediate anymore.
    float* v = (float*)d_ws;

    // A: w reduction -> v
    reduce_w_kernel<<<COUT, 64, 0, stream>>>(w_pw, v);

    // Fused B+C: per-block s-tile from x, then all-o pointwise with NT stores
    fused_bc_kernel<<<NBC, 256, 0, stream>>>(x, v, out);
}

// Round 7
// 358.173 us; speedup vs baseline: 1.1675x; 1.1675x over previous
//
#include <hip/hip_runtime.h>

// Problem constants
#define B_   32
#define CIN  256
#define H_   64
#define W_   64
#define COUT 512
#define G_   9
#define CPG_IN  28          // 252 used input channels / 9 groups
#define HW_  (H_*W_)        // 4096
#define HW4_ (HW_/4)        // 1024 float4 per plane

// Padded s' geometry: padded coord = real + 1; halo (zeros) removes ALL bounds
// checks in kernel C. Row stride 68 floats = 272 B (16B-aligned); plane
// 66*68*4 = 17952 B (16B-aligned). C's f4 loads land on 16B boundaries.
#define HP 66
#define WP 68
#define PLANE (HP*WP)        // 4488 floats
#define VSTRIDE 16           // v padded to [512][16] for aligned scalar loads

typedef float f4 __attribute__((ext_vector_type(4)));

// ---------------------------------------------------------------------------
// Kernel A: v[o][g] = sum of w_pw[o, c] over group g's columns.
// g = c/56 for c < 504; c in [504,512) folds into centre group 4.
// One block (64 threads) per o; per-group wave shuffle reduction, no atomics.
// ---------------------------------------------------------------------------
__global__ __launch_bounds__(64) void reduce_w_kernel(const float* __restrict__ w,
                                                      float* __restrict__ v) {
    const int o = blockIdx.x;
    const int t = threadIdx.x;          // 0..63
    const float* row = w + o * COUT;
#pragma unroll
    for (int g = 0; g < G_; ++g) {
        float val = (t < 56) ? row[g * 56 + t] : 0.0f;
        if (g == 4 && t >= 56) val = row[504 + (t - 56)];   // miss channels -> centre
#pragma unroll
        for (int off = 32; off; off >>= 1) val += __shfl_down(val, off);
        if (t == 0) v[o * VSTRIDE + g] = val;
    }
}

// ---------------------------------------------------------------------------
// Kernel B: s'[b][g][h+1][w+1] = sum_{k<28} x[b][28g+k][h][w]  (+ halo zeroing)
// x is touch-once -> nontemporal loads; s' must stay L2/L3-resident -> normal
// stores. Interior stores are scalar (dest is +1-shifted, not 16B-aligned).
// Blocks >= NMAIN zero the halo of one (b,g) plane each (re-poisoned each run).
// ---------------------------------------------------------------------------
#define NMAIN (B_*G_*HW4_/256)   // 1152 main blocks
__global__ __launch_bounds__(256) void group_sum_kernel(const float* __restrict__ x,
                                                        float* __restrict__ s) {
    const int bid = blockIdx.x;
    const int tid = threadIdx.x;
    if (bid < NMAIN) {
        const int idx = bid * 256 + tid;   // float4 units; total B*9*1024
        const int m  = idx & (HW4_ - 1);
        const int gb = idx >> 10;          // b*9 + g
        const int g  = gb % G_;
        const int b  = gb / G_;
        const int hh = m >> 4;             // row 0..63
        const int ww = (m & 15) * 4;       // col 0..60 step 4
        const f4* xp = (const f4*)x;
        long base = ((long)(b * CIN + g * CPG_IN)) * HW4_ + m;
        f4 acc = (f4)0.0f;
#pragma unroll
        for (int k = 0; k < CPG_IN; ++k) {
            acc += __builtin_nontemporal_load(xp + base + (long)k * HW4_);
        }
        float* sp = s + (long)gb * PLANE + (hh + 1) * WP + (ww + 1);
        sp[0] = acc.x; sp[1] = acc.y; sp[2] = acc.z; sp[3] = acc.w;
    } else {
        // Halo zeroing: rows 0 & 65 full width; cols {0,65,66,67} for rows 1..64.
        const int plane = bid - NMAIN;       // 0..287 = b*9+g
        float* sp = s + (long)plane * PLANE;
#pragma unroll
        for (int pass = 0; pass < 2; ++pass) {
            int i = tid + pass * 256;
            if (i < 392) {
                int p;
                if (i < 68)       p = i;                       // top row
                else if (i < 136) p = 65 * WP + (i - 68);      // bottom row
                else {
                    int k = i - 136;                           // 0..255
                    int r = 1 + (k >> 2);                      // rows 1..64
                    int c = k & 3;                             // 0->col0, 1..3->65..67
                    p = r * WP + (c == 0 ? 0 : 64 + c);
                }
                sp[p] = 0.0f;
            }
        }
    }
}

// ---------------------------------------------------------------------------
// Kernel C: out[b][o][h][w] = sum_g v[o][g] * s'[b][g][h+g/3][w+g%3] (padded)
// NO LDS, NO barrier, NO bounds checks: per thread, 18 aligned f4 loads from
// the L2/L3-resident padded s' (9 planes x 8 cols covering all three gj
// shifts), then oi-OUTER loop: 4-reg accumulator, one NT store per output
// plane. O_TILE=32: 18 preloads amortized over 32 output planes. NT stores:
// touch-once output must not occupy L2 (round-3 A/B: normal stores -14 us).
// ---------------------------------------------------------------------------
#define O_TILE 32
#define H_TILE 16

__global__ __launch_bounds__(256, 4) void shift_pw_kernel(const float* __restrict__ s,
                                                          const float* __restrict__ v,
                                                          float* __restrict__ out) {
    const int bid = blockIdx.x;
    const int ot  = bid & 15;         // 16 o-tiles
    const int ht  = (bid >> 4) & 3;   // 4 h-tiles
    const int b   = bid >> 6;         // 32 batches
    const int h0  = ht * H_TILE;
    const int tid = threadIdx.x;
    const int o0  = ot * O_TILE;
    const int w0  = (tid & 15) * 4;   // 16 float4-columns cover W=64
    const int hl  = tid >> 4;         // 16 rows

    // Preload oi-invariant s-values: per g, padded row h0+hl+g/3, cols w0..w0+7.
    // All loads 16B-aligned (row stride 272B, w0*4 multiple of 16).
    const float* sb = s + (long)b * G_ * PLANE;
    f4 sa[G_], sbv[G_];
#pragma unroll
    for (int g = 0; g < G_; ++g) {
        const int gi = g / 3;
        const float* rp = sb + g * PLANE + (h0 + hl + gi) * WP + w0;
        sa[g]  = *(const f4*)rp;
        sbv[g] = *(const f4*)(rp + 4);
    }

    long obase = (((long)b * COUT + o0) * H_ + (h0 + hl)) * W_ + w0;
    const float* vp = v + o0 * VSTRIDE;   // block-uniform -> scalar loads
#pragma unroll
    for (int oi = 0; oi < O_TILE; ++oi) {
        f4 acc = (f4)0.0f;
#pragma unroll
        for (int g = 0; g < G_; ++g) {
            const int gj = g - (g / 3) * 3;
            const float vv = vp[oi * VSTRIDE + g];
            float s0, s1, s2, s3;
            if (gj == 0)      { s0 = sa[g].x; s1 = sa[g].y; s2 = sa[g].z; s3 = sa[g].w; }
            else if (gj == 1) { s0 = sa[g].y; s1 = sa[g].z; s2 = sa[g].w; s3 = sbv[g].x; }
            else              { s0 = sa[g].z; s1 = sa[g].w; s2 = sbv[g].x; s3 = sbv[g].y; }
            acc.x += vv * s0;
            acc.y += vv * s1;
            acc.z += vv * s2;
            acc.w += vv * s3;
        }
        // out is touch-once -> nontemporal; each wave's store = 1 KiB contiguous
        __builtin_nontemporal_store(acc, (f4*)(out + obase + (long)oi * HW_));
    }
}

// ---------------------------------------------------------------------------
extern "C" void kernel_launch(void* const* d_in, const int* in_sizes, int n_in,
                              void* d_out, int out_size, void* d_ws, size_t ws_size,
                              hipStream_t stream) {
    const float* x    = (const float*)d_in[0];   // (32,256,64,64) fp32
    const float* w_pw = (const float*)d_in[1];   // (512,512) fp32
    float* out = (float*)d_out;                  // (32,512,64,64) fp32

    // workspace layout: v[512][16] at 0 (32 KiB exactly), padded s' at 32 KiB
    // (32*9*4488 floats = 5.17 MiB)
    float* v = (float*)d_ws;
    float* s = (float*)((char*)d_ws + 32768);

    // A: w reduction -> v[512][16]
    reduce_w_kernel<<<COUT, 64, 0, stream>>>(w_pw, v);

    // B: x group sum -> padded s' (+ 288 halo-zeroing blocks)
    group_sum_kernel<<<NMAIN + B_ * G_, 256, 0, stream>>>(x, s);

    // C: main shifted pointwise, LDS-free, O_TILE=32
    shift_pw_kernel<<<B_ * (H_ / H_TILE) * (COUT / O_TILE), 256, 0, stream>>>(s, v, out);
}